// Round 9
// baseline (1000.074 us; speedup 1.0000x reference)
//
#include <hip/hip_runtime.h>
#include <hip/hip_fp16.h>

#define N_NODES 50000
#define IN_F    128
#define HID_F   128
#define OUT_F   64
#define E_EDGES 800000

// Fine buckets: 16 rows = one aggregation block. No sort needed — LDS fp32
// atomicAdd (ds_add_f32, fire-and-forget) scatters edges into acc[16][128]
// in arrival order. Round-5 lesson: NEVER per-row global scatter (64B/edge
// writeback); bucket-contiguous bin runs keep write amp ~2x at RPB=16.
#define RPB   16
#define NBUCK ((N_NODES + RPB - 1) / RPB)            // 3125
#define BCAP  384                                    // mean 256, +8 sigma
#define BIN_T   512
#define BIN_EPT 16
#define BIN_EPB (BIN_T * BIN_EPT)                    // 8192 edges per block
#define BIN_NB  ((E_EDGES + BIN_EPB - 1) / BIN_EPB)  // 98
#define G0_NB   ((N_NODES + 127) / 128)              // 391 gemm0 blocks

typedef _Float16 half8 __attribute__((ext_vector_type(8)));
typedef float    floatx4 __attribute__((ext_vector_type(4)));

// ---------------- Prep: zero gfill + convert W0/W1 to fp16 transposed -------
__global__ __launch_bounds__(256) void prep_kernel(const float* __restrict__ W0,
                                                   const float* __restrict__ W1,
                                                   __half* __restrict__ wt0,
                                                   __half* __restrict__ wt1,
                                                   int* __restrict__ gfill) {
    int tid = blockIdx.x * 256 + threadIdx.x;
    if (tid < IN_F * HID_F) {               // wt0[n][k] = W0[k][n], 128x128
        int k = tid >> 7, n = tid & 127;
        wt0[n * IN_F + k] = __float2half(W0[tid]);
    }
    if (tid < HID_F * OUT_F) {              // wt1[n][k] = W1[k][n], 128x64
        int k = tid / OUT_F, n = tid % OUT_F;
        wt1[n * HID_F + k] = __float2half(W1[tid]);
    }
    if (tid < 2 * NBUCK) gfill[tid] = 0;
}

// ---------------- Bin (y=0,1) + layer-0 GEMM (y=2) in one dispatch ----------
// gemm0 never depended on bin; co-dispatching hides it here (sort is gone).
union BinLds {
    struct { int lhist[NBUCK]; int lbase[NBUCK]; } h;   // 25 KB
    _Float16 ws[HID_F * (IN_F + 8)];                    // 34.8 KB (dominates)
};

__global__ __launch_bounds__(BIN_T) void bin_gemm_kernel(
        const int* __restrict__ row0, const int* __restrict__ col0, const float* __restrict__ val0,
        const int* __restrict__ row1, const int* __restrict__ col1, const float* __restrict__ val1,
        int* __restrict__ gfill, int2* __restrict__ bcv0, int2* __restrict__ bcv1,
        const float* __restrict__ x, const __half* __restrict__ wt0,
        __half* __restrict__ sup0, int M) {
    __shared__ BinLds lds;
    const int tid = threadIdx.x;

    if (blockIdx.y < 2) {
        // ---------------- bucket binning ----------------
        if (blockIdx.x >= BIN_NB) return;
        const int g = blockIdx.y;
        const int*   rowi = g ? row1 : row0;
        const int*   coli = g ? col1 : col0;
        const float* vali = g ? val1 : val0;
        int*  gf  = gfill + g * NBUCK;
        int2* bcv = g ? bcv1 : bcv0;

        for (int i = tid; i < NBUCK; i += BIN_T) lds.h.lhist[i] = 0;
        __syncthreads();

        int rnk[BIN_EPT], bkt[BIN_EPT], cl[BIN_EPT], rw[BIN_EPT];
        float vl[BIN_EPT];
        const int e0 = blockIdx.x * BIN_EPB;
#pragma unroll
        for (int i = 0; i < BIN_EPT; ++i) {
            const int e = e0 + i * BIN_T + tid;
            bkt[i] = -1;
            if (e < E_EDGES) {
                const int r = rowi[e];
                rw[i] = r; cl[i] = coli[e]; vl[i] = vali[e];
                bkt[i] = r >> 4;                       // bucket = r / RPB
                rnk[i] = atomicAdd(&lds.h.lhist[bkt[i]], 1);
            }
        }
        __syncthreads();
        for (int i = tid; i < NBUCK; i += BIN_T) {
            const int c = lds.h.lhist[i];
            lds.h.lbase[i] = c ? atomicAdd(&gf[i], c) : 0;
        }
        __syncthreads();
#pragma unroll
        for (int i = 0; i < BIN_EPT; ++i) {
            if (bkt[i] >= 0) {
                const int pos = lds.h.lbase[bkt[i]] + rnk[i];
                if (pos < BCAP)
                    bcv[(long)bkt[i] * BCAP + pos] =
                        make_int2(((rw[i] & (RPB - 1)) << 16) | cl[i], __float_as_int(vl[i]));
            }
        }
    } else {
        // ---------------- layer-0 GEMM: 128 rows per block ----------
        constexpr int KP = IN_F + 8;
        constexpr int NT = HID_F / 16;
        for (int c = tid; c < HID_F * (IN_F / 8); c += BIN_T) {
            const int n = c / (IN_F / 8), ko = (c % (IN_F / 8)) * 8;
            *(half8*)&lds.ws[n * KP + ko] = *(const half8*)(wt0 + n * IN_F + ko);
        }
        __syncthreads();

        const int wv = tid >> 6, lane = tid & 63;
        const int quad = lane >> 4, l16 = lane & 15;
        const int rowb = blockIdx.x * 128 + wv * 16;
        const int arow = rowb + l16;

        floatx4 acc[NT] = {};
#pragma unroll
        for (int ks = 0; ks < IN_F; ks += 32) {
            half8 af = {};
            if (arow < M) {
                const float4* p = (const float4*)(x + (long)arow * IN_F + ks + quad * 8);
                float4 u = p[0], w = p[1];
                af[0] = (_Float16)u.x; af[1] = (_Float16)u.y;
                af[2] = (_Float16)u.z; af[3] = (_Float16)u.w;
                af[4] = (_Float16)w.x; af[5] = (_Float16)w.y;
                af[6] = (_Float16)w.z; af[7] = (_Float16)w.w;
            }
#pragma unroll
            for (int t = 0; t < NT; ++t) {
                half8 bf = *(const half8*)&lds.ws[(t * 16 + l16) * KP + ks + quad * 8];
                acc[t] = __builtin_amdgcn_mfma_f32_16x16x32_f16(af, bf, acc[t], 0, 0, 0);
            }
        }
#pragma unroll
        for (int t = 0; t < NT; ++t) {
            const int col = t * 16 + l16;
#pragma unroll
            for (int i = 0; i < 4; ++i) {
                const int row = rowb + quad * 4 + i;
                if (row < M) sup0[(long)row * HID_F + col] = __float2half(acc[t][i]);
            }
        }
    }
}

// ---------------- Fused layer-0 aggregate (unsorted) + relu + gemm1 --------
// Block = bucket = 16 rows. Edges processed in arrival order; products
// scattered via LDS float atomicAdd (no return -> no dep chain; 2-way bank
// alias only). 8-deep gather (measured best: round-0 181 vs round-7 186).
__global__ __launch_bounds__(256) void agg_gemm_kernel(const int* __restrict__ gfill,
                                                       const int2* __restrict__ bcv,
                                                       const __half* __restrict__ sup,
                                                       const float* __restrict__ bias,
                                                       const __half* __restrict__ wt1,
                                                       __half* __restrict__ sup1) {
    constexpr int AS = 130;           // acc row stride in dwords (bank-stagger)
    constexpr int HP = HID_F + 8;     // ht row stride in halves
    __shared__ float    acc[16 * AS]; // 8.3 KB
    __shared__ _Float16 ht[16 * HP];  // 4.4 KB
    const int tid  = threadIdx.x;
    const int wv   = tid >> 6;
    const int lane = tid & 63;
    const int b    = blockIdx.x;
    const int cnt  = min(gfill[b], BCAP);
    const int2* eb = bcv + (long)b * BCAP;
    const int f0   = lane * 2;

    for (int i = tid; i < 16 * AS; i += 256) acc[i] = 0.f;
    __syncthreads();

    // ---- Phase 1: waves take disjoint 64-edge chunks ----
    for (int base = wv * 64; base < cnt; base += 256) {
        const int m = min(64, cnt - base);
        int2 cvl = make_int2(0, 0);
        if (lane < m) cvl = eb[base + lane];         // lanes >= m give (0,0)
        for (int j = 0; j < m; j += 8) {
            int   pr[8];
            float v[8];
#pragma unroll
            for (int q = 0; q < 8; ++q) {
                pr[q] = __shfl(cvl.x, j + q, 64);
                v[q]  = __int_as_float(__shfl(cvl.y, j + q, 64));
            }
            __half2 s[8];
#pragma unroll
            for (int q = 0; q < 8; ++q)
                s[q] = *(const __half2*)(sup + (long)(pr[q] & 0xFFFF) * HID_F + f0);
#pragma unroll
            for (int q = 0; q < 8; ++q) {
                float2 g = __half22float2(s[q]);
                const int rl = pr[q] >> 16;          // padded lanes: rl=0, v=0
                atomicAdd(&acc[rl * AS + f0],     v[q] * g.x);
                atomicAdd(&acc[rl * AS + f0 + 1], v[q] * g.y);
            }
        }
    }
    __syncthreads();

    // ---- bias + relu -> ht fp16 ----
#pragma unroll
    for (int i = 0; i < 4; ++i) {
        const int r = wv * 4 + i;
        float a0 = acc[r * AS + f0]     + bias[f0];
        float a1 = acc[r * AS + f0 + 1] + bias[f0 + 1];
        a0 = a0 > 0.f ? a0 : 0.f;
        a1 = a1 > 0.f ? a1 : 0.f;
        *(__half2*)&ht[r * HP + f0] = __floats2half2_rn(a0, a1);
    }
    __syncthreads();

    // ---- Phase 2: 16x64 gemm1 tile, wave wv -> cols wv*16..+15 ----
    const int quad = lane >> 4, l16 = lane & 15;
    floatx4 oacc = {};
#pragma unroll
    for (int ks = 0; ks < HID_F; ks += 32) {
        half8 af = *(const half8*)&ht[l16 * HP + ks + quad * 8];
        half8 bf = *(const half8*)(wt1 + (long)(wv * 16 + l16) * HID_F + ks + quad * 8);
        oacc = __builtin_amdgcn_mfma_f32_16x16x32_f16(af, bf, oacc, 0, 0, 0);
    }
    const int r0 = b * 16;
#pragma unroll
    for (int i = 0; i < 4; ++i) {
        const int row = r0 + quad * 4 + i;
        sup1[(long)row * OUT_F + wv * 16 + l16] = __float2half(oacc[i]);
    }
}

// ---------------- SpMM layer 1: unsorted bucket, LDS-atomic accumulate -----
__global__ __launch_bounds__(256) void spmm_l1_kernel(const int* __restrict__ gfill,
                                                      const int2* __restrict__ bcv,
                                                      const __half* __restrict__ sup,
                                                      const float* __restrict__ bias,
                                                      float* __restrict__ out) {
    constexpr int AS1 = 66;           // acc row stride in dwords
    __shared__ float acc[16 * AS1];   // 4.2 KB
    const int tid  = threadIdx.x;
    const int wv   = tid >> 6;
    const int lane = tid & 63;
    const int b    = blockIdx.x;
    const int cnt  = min(gfill[NBUCK + b], BCAP);
    const int2* eb = bcv + (long)b * BCAP;
    const int eh = lane >> 5;
    const int li = lane & 31;
    const int f0 = li * 2;

    for (int i = tid; i < 16 * AS1; i += 256) acc[i] = 0.f;
    __syncthreads();

    for (int base = wv * 64; base < cnt; base += 256) {
        const int m = min(64, cnt - base);
        int2 cvl = make_int2(0, 0);
        if (lane < m) cvl = eb[base + lane];
        for (int j = 0; j < m; j += 16) {            // 2 edges per batch slot
            int   pr[8];
            float v[8];
#pragma unroll
            for (int q = 0; q < 8; ++q) {
                const int src = j + 2 * q + eh;
                pr[q] = __shfl(cvl.x, src, 64);
                v[q]  = __int_as_float(__shfl(cvl.y, src, 64));
            }
            __half2 s[8];
#pragma unroll
            for (int q = 0; q < 8; ++q)
                s[q] = *(const __half2*)(sup + (long)(pr[q] & 0xFFFF) * OUT_F + f0);
#pragma unroll
            for (int q = 0; q < 8; ++q) {
                float2 g = __half22float2(s[q]);
                const int rl = pr[q] >> 16;
                atomicAdd(&acc[rl * AS1 + f0],     v[q] * g.x);
                atomicAdd(&acc[rl * AS1 + f0 + 1], v[q] * g.y);
            }
        }
    }
    __syncthreads();

    // ---- write out: thread t -> (row t>>4, feats (t&15)*4..+4) ----
    const int r  = tid >> 4;
    const int fb = (tid & 15) * 4;
    const int row = b * 16 + r;
    float4 o;
    o.x = acc[r * AS1 + fb]     + bias[fb];
    o.y = acc[r * AS1 + fb + 1] + bias[fb + 1];
    o.z = acc[r * AS1 + fb + 2] + bias[fb + 2];
    o.w = acc[r * AS1 + fb + 3] + bias[fb + 3];
    *(float4*)(out + (long)row * OUT_F + fb) = o;
}

extern "C" void kernel_launch(void* const* d_in, const int* in_sizes, int n_in,
                              void* d_out, int out_size, void* d_ws, size_t ws_size,
                              hipStream_t stream) {
    const float* x    = (const float*)d_in[0];
    const int*   row0 = (const int*)d_in[1];
    const int*   col0 = (const int*)d_in[2];
    const float* val0 = (const float*)d_in[3];
    const int*   row1 = (const int*)d_in[4];
    const int*   col1 = (const int*)d_in[5];
    const float* val1 = (const float*)d_in[6];
    const float* W0   = (const float*)d_in[7];
    const float* b0   = (const float*)d_in[8];
    const float* W1   = (const float*)d_in[9];
    const float* b1   = (const float*)d_in[10];
    float* out = (float*)d_out;

    // Workspace: sup0 (N*128 fp16), sup1 (N*64 fp16), bcv0/1 (9.6 MB each),
    // gfill (2*NBUCK), wt0, wt1.  Total ~39 MB.
    __half* sup0 = (__half*)d_ws;
    __half* sup1 = sup0 + (long)N_NODES * HID_F;
    int2* bcv0   = (int2*)(sup1 + (long)N_NODES * OUT_F);
    int2* bcv1   = bcv0 + (long)NBUCK * BCAP;
    int*  gfill  = (int*)(bcv1 + (long)NBUCK * BCAP);
    __half* wt0  = (__half*)(gfill + 2 * NBUCK + 2);   // [HID_F][IN_F]
    __half* wt1  = wt0 + IN_F * HID_F;                 // [OUT_F][HID_F]

    // ---- Prep (zero gfill + weight transpose) ----
    prep_kernel<<<(IN_F * HID_F + 255) / 256, 256, 0, stream>>>(W0, W1, wt0, wt1, gfill);

    // ---- Bin (both graphs) || layer-0 GEMM, one dispatch ----
    bin_gemm_kernel<<<dim3(G0_NB, 3), BIN_T, 0, stream>>>(
        row0, col0, val0, row1, col1, val1, gfill, bcv0, bcv1,
        x, wt0, sup0, N_NODES);

    // ---- Fused: layer-0 aggregate + bias/relu + layer-1 GEMM ----
    agg_gemm_kernel<<<NBUCK, 256, 0, stream>>>(gfill, bcv0, sup0, b0, wt1, sup1);

    // ---- Layer-1 aggregate ----
    spmm_l1_kernel<<<NBUCK, 256, 0, stream>>>(gfill, bcv1, sup1, b1, out);
}

// Round 10
// 177.877 us; speedup vs baseline: 5.6223x; 5.6223x over previous
//
#include <hip/hip_runtime.h>
#include <hip/hip_fp16.h>

#define N_NODES 50000
#define IN_F    128
#define HID_F   128
#define OUT_F   64
#define E_EDGES 800000

// Fine buckets: 16 rows = one aggregation block. Edges arrive unsorted; the
// CONSUMER kernel counting-sorts its ~256 edges in LDS (3 KB) then uses
// register accumulation.  Measured lessons honored:
//  - r5: per-row global scatter = 64B/edge writeback (94us). Bin runs stay
//    bucket-contiguous.
//  - r9: LDS f32 atomicAdd scatter = 102M ds_add = 588us. Registers only.
//  - r7: gather is memory-system bound; 8-deep batch is the measured best.
#define RPB   16
#define NBUCK ((N_NODES + RPB - 1) / RPB)            // 3125
#define BCAP  384                                    // mean 256, +8 sigma
#define BIN_T   512
#define BIN_EPT 16
#define BIN_EPB (BIN_T * BIN_EPT)                    // 8192 edges per block
#define BIN_NB  ((E_EDGES + BIN_EPB - 1) / BIN_EPB)  // 98
#define G0_NB   ((N_NODES + 127) / 128)              // 391 gemm0 blocks

typedef _Float16 half8 __attribute__((ext_vector_type(8)));
typedef float    floatx4 __attribute__((ext_vector_type(4)));

// ---------------- Prep: zero gfill + convert W0/W1 to fp16 transposed -------
__global__ __launch_bounds__(256) void prep_kernel(const float* __restrict__ W0,
                                                   const float* __restrict__ W1,
                                                   __half* __restrict__ wt0,
                                                   __half* __restrict__ wt1,
                                                   int* __restrict__ gfill) {
    int tid = blockIdx.x * 256 + threadIdx.x;
    if (tid < IN_F * HID_F) {               // wt0[n][k] = W0[k][n], 128x128
        int k = tid >> 7, n = tid & 127;
        wt0[n * IN_F + k] = __float2half(W0[tid]);
    }
    if (tid < HID_F * OUT_F) {              // wt1[n][k] = W1[k][n], 128x64
        int k = tid / OUT_F, n = tid % OUT_F;
        wt1[n * HID_F + k] = __float2half(W1[tid]);
    }
    if (tid < 2 * NBUCK) gfill[tid] = 0;
}

// ---------------- Bin (y=0,1) + layer-0 GEMM (y=2) in one dispatch ----------
union BinLds {
    struct { int lhist[NBUCK]; int lbase[NBUCK]; } h;   // 25 KB
    _Float16 ws[HID_F * (IN_F + 8)];                    // 34.8 KB (dominates)
};

__global__ __launch_bounds__(BIN_T) void bin_gemm_kernel(
        const int* __restrict__ row0, const int* __restrict__ col0, const float* __restrict__ val0,
        const int* __restrict__ row1, const int* __restrict__ col1, const float* __restrict__ val1,
        int* __restrict__ gfill, int2* __restrict__ bcv0, int2* __restrict__ bcv1,
        const float* __restrict__ x, const __half* __restrict__ wt0,
        __half* __restrict__ sup0, int M) {
    __shared__ BinLds lds;
    const int tid = threadIdx.x;

    if (blockIdx.y < 2) {
        // ---------------- bucket binning ----------------
        if (blockIdx.x >= BIN_NB) return;
        const int g = blockIdx.y;
        const int*   rowi = g ? row1 : row0;
        const int*   coli = g ? col1 : col0;
        const float* vali = g ? val1 : val0;
        int*  gf  = gfill + g * NBUCK;
        int2* bcv = g ? bcv1 : bcv0;

        for (int i = tid; i < NBUCK; i += BIN_T) lds.h.lhist[i] = 0;
        __syncthreads();

        int rnk[BIN_EPT], bkt[BIN_EPT], cl[BIN_EPT], rw[BIN_EPT];
        float vl[BIN_EPT];
        const int e0 = blockIdx.x * BIN_EPB;
#pragma unroll
        for (int i = 0; i < BIN_EPT; ++i) {
            const int e = e0 + i * BIN_T + tid;
            bkt[i] = -1;
            if (e < E_EDGES) {
                const int r = rowi[e];
                rw[i] = r; cl[i] = coli[e]; vl[i] = vali[e];
                bkt[i] = r >> 4;                       // bucket = r / RPB
                rnk[i] = atomicAdd(&lds.h.lhist[bkt[i]], 1);
            }
        }
        __syncthreads();
        for (int i = tid; i < NBUCK; i += BIN_T) {
            const int c = lds.h.lhist[i];
            lds.h.lbase[i] = c ? atomicAdd(&gf[i], c) : 0;
        }
        __syncthreads();
#pragma unroll
        for (int i = 0; i < BIN_EPT; ++i) {
            if (bkt[i] >= 0) {
                const int pos = lds.h.lbase[bkt[i]] + rnk[i];
                if (pos < BCAP)
                    bcv[(long)bkt[i] * BCAP + pos] =
                        make_int2(((rw[i] & (RPB - 1)) << 16) | cl[i], __float_as_int(vl[i]));
            }
        }
    } else {
        // ---------------- layer-0 GEMM: 128 rows per block ----------
        constexpr int KP = IN_F + 8;
        constexpr int NT = HID_F / 16;
        for (int c = tid; c < HID_F * (IN_F / 8); c += BIN_T) {
            const int n = c / (IN_F / 8), ko = (c % (IN_F / 8)) * 8;
            *(half8*)&lds.ws[n * KP + ko] = *(const half8*)(wt0 + n * IN_F + ko);
        }
        __syncthreads();

        const int wv = tid >> 6, lane = tid & 63;
        const int quad = lane >> 4, l16 = lane & 15;
        const int rowb = blockIdx.x * 128 + wv * 16;
        const int arow = rowb + l16;

        floatx4 acc[NT] = {};
#pragma unroll
        for (int ks = 0; ks < IN_F; ks += 32) {
            half8 af = {};
            if (arow < M) {
                const float4* p = (const float4*)(x + (long)arow * IN_F + ks + quad * 8);
                float4 u = p[0], w = p[1];
                af[0] = (_Float16)u.x; af[1] = (_Float16)u.y;
                af[2] = (_Float16)u.z; af[3] = (_Float16)u.w;
                af[4] = (_Float16)w.x; af[5] = (_Float16)w.y;
                af[6] = (_Float16)w.z; af[7] = (_Float16)w.w;
            }
#pragma unroll
            for (int t = 0; t < NT; ++t) {
                half8 bf = *(const half8*)&lds.ws[(t * 16 + l16) * KP + ks + quad * 8];
                acc[t] = __builtin_amdgcn_mfma_f32_16x16x32_f16(af, bf, acc[t], 0, 0, 0);
            }
        }
#pragma unroll
        for (int t = 0; t < NT; ++t) {
            const int col = t * 16 + l16;
#pragma unroll
            for (int i = 0; i < 4; ++i) {
                const int row = rowb + quad * 4 + i;
                if (row < M) sup0[(long)row * HID_F + col] = __float2half(acc[t][i]);
            }
        }
    }
}

// ---------------- Fused: LDS sort + layer-0 aggregate + relu + gemm1 -------
// Block = bucket = 16 rows, ~256 edges. Counting sort in LDS (hist over 16
// bins + serial scan + scatter), then per-wave register aggregation with
// broadcast ds_read of edges (no shuffles) and 8-deep global gather.
__global__ __launch_bounds__(256) void agg_gemm_kernel(const int* __restrict__ gfill,
                                                       const int2* __restrict__ bcv,
                                                       const __half* __restrict__ sup,
                                                       const float* __restrict__ bias,
                                                       const __half* __restrict__ wt1,
                                                       __half* __restrict__ sup1) {
    constexpr int HP = HID_F + 8;     // ht row stride in halves
    __shared__ int2 sbuf[BCAP];       // 3 KB sorted edges
    __shared__ int  cur[RPB];
    __shared__ int  st[RPB + 1];
    __shared__ _Float16 ht[16 * HP];  // 4.4 KB
    const int tid  = threadIdx.x;
    const int wv   = tid >> 6;
    const int lane = tid & 63;
    const int b    = blockIdx.x;
    const int cnt  = min(gfill[b], BCAP);
    const int2* eb = bcv + (long)b * BCAP;
    const int f0   = lane * 2;

    // ---- LDS counting sort of the bucket's edges by local row ----
    int2 ed[2]; int rnk[2];
    if (tid < RPB) cur[tid] = 0;
    __syncthreads();
#pragma unroll
    for (int k = 0; k < 2; ++k) {
        const int e = tid + k * 256;
        if (e < cnt) {
            ed[k] = eb[e];
            rnk[k] = atomicAdd(&cur[ed[k].x >> 16], 1);
        }
    }
    __syncthreads();
    if (tid == 0) {
        int s = 0;
#pragma unroll
        for (int i = 0; i < RPB; ++i) { st[i] = s; s += cur[i]; }
        st[RPB] = s;
    }
    __syncthreads();
#pragma unroll
    for (int k = 0; k < 2; ++k) {
        const int e = tid + k * 256;
        if (e < cnt) sbuf[st[ed[k].x >> 16] + rnk[k]] = ed[k];
    }
    __syncthreads();

    // ---- Phase 1: wave wv aggregates rows wv*4..+3 (register acc) ----
#pragma unroll
    for (int i = 0; i < 4; ++i) {
        const int r  = wv * 4 + i;
        const int s0 = st[r], s1 = st[r + 1];
        float acc0 = bias[f0];
        float acc1 = bias[f0 + 1];
        for (int j = s0; j < s1; j += 8) {
            const int n = s1 - j;
            int   pr[8];
            float v[8];
#pragma unroll
            for (int q = 0; q < 8; ++q) {            // broadcast LDS reads
                if (q < n) {
                    int2 e2 = sbuf[j + q];
                    pr[q] = e2.x & 0xFFFF;
                    v[q]  = __int_as_float(e2.y);
                } else { pr[q] = 0; v[q] = 0.f; }    // masked: gather row 0, v=0
            }
            __half2 s8[8];
#pragma unroll
            for (int q = 0; q < 8; ++q)              // 8 gathers in flight
                s8[q] = *(const __half2*)(sup + (long)pr[q] * HID_F + f0);
#pragma unroll
            for (int q = 0; q < 8; ++q) {
                float2 g = __half22float2(s8[q]);
                acc0 += v[q] * g.x; acc1 += v[q] * g.y;
            }
        }
        acc0 = acc0 > 0.f ? acc0 : 0.f;              // relu
        acc1 = acc1 > 0.f ? acc1 : 0.f;
        *(__half2*)&ht[r * HP + f0] = __floats2half2_rn(acc0, acc1);
    }
    __syncthreads();

    // ---- Phase 2: 16x64 gemm1 tile, wave wv -> cols wv*16..+15 ----
    const int quad = lane >> 4, l16 = lane & 15;
    floatx4 oacc = {};
#pragma unroll
    for (int ks = 0; ks < HID_F; ks += 32) {
        half8 af = *(const half8*)&ht[l16 * HP + ks + quad * 8];
        half8 bf = *(const half8*)(wt1 + (long)(wv * 16 + l16) * HID_F + ks + quad * 8);
        oacc = __builtin_amdgcn_mfma_f32_16x16x32_f16(af, bf, oacc, 0, 0, 0);
    }
    const int r0 = b * 16;
#pragma unroll
    for (int i = 0; i < 4; ++i) {
        const int row = r0 + quad * 4 + i;
        sup1[(long)row * OUT_F + wv * 16 + l16] = __float2half(oacc[i]);
    }
}

// ---------------- SpMM layer 1: LDS sort + half-wave register aggregate ----
__global__ __launch_bounds__(256) void spmm_l1_kernel(const int* __restrict__ gfill,
                                                      const int2* __restrict__ bcv,
                                                      const __half* __restrict__ sup,
                                                      const float* __restrict__ bias,
                                                      float* __restrict__ out) {
    __shared__ int2 sbuf[BCAP];
    __shared__ int  cur[RPB];
    __shared__ int  st[RPB + 1];
    const int tid  = threadIdx.x;
    const int wv   = tid >> 6;
    const int lane = tid & 63;
    const int b    = blockIdx.x;
    const int cnt  = min(gfill[NBUCK + b], BCAP);
    const int2* eb = bcv + (long)b * BCAP;
    const int eh = lane >> 5;
    const int li = lane & 31;
    const int f0 = li * 2;

    // ---- LDS counting sort ----
    int2 ed[2]; int rnk[2];
    if (tid < RPB) cur[tid] = 0;
    __syncthreads();
#pragma unroll
    for (int k = 0; k < 2; ++k) {
        const int e = tid + k * 256;
        if (e < cnt) {
            ed[k] = eb[e];
            rnk[k] = atomicAdd(&cur[ed[k].x >> 16], 1);
        }
    }
    __syncthreads();
    if (tid == 0) {
        int s = 0;
#pragma unroll
        for (int i = 0; i < RPB; ++i) { st[i] = s; s += cur[i]; }
        st[RPB] = s;
    }
    __syncthreads();
#pragma unroll
    for (int k = 0; k < 2; ++k) {
        const int e = tid + k * 256;
        if (e < cnt) sbuf[st[ed[k].x >> 16] + rnk[k]] = ed[k];
    }
    __syncthreads();

    // ---- wave wv -> rows wv*4..+3; half-waves split even/odd edges ----
#pragma unroll
    for (int i = 0; i < 4; ++i) {
        const int r  = wv * 4 + i;
        const int s0 = st[r], s1 = st[r + 1];
        float acc0 = eh ? 0.f : bias[f0];
        float acc1 = eh ? 0.f : bias[f0 + 1];
        for (int j = s0; j < s1; j += 16) {
            int   pr[8];
            float v[8];
#pragma unroll
            for (int q = 0; q < 8; ++q) {
                const int idx = j + 2 * q + eh;
                if (idx < s1) {
                    int2 e2 = sbuf[idx];
                    pr[q] = e2.x & 0xFFFF;
                    v[q]  = __int_as_float(e2.y);
                } else { pr[q] = 0; v[q] = 0.f; }
            }
            __half2 s8[8];
#pragma unroll
            for (int q = 0; q < 8; ++q)
                s8[q] = *(const __half2*)(sup + (long)pr[q] * OUT_F + f0);
#pragma unroll
            for (int q = 0; q < 8; ++q) {
                float2 g = __half22float2(s8[q]);
                acc0 += v[q] * g.x; acc1 += v[q] * g.y;
            }
        }
        acc0 += __shfl_xor(acc0, 32, 64);
        acc1 += __shfl_xor(acc1, 32, 64);
        if (eh == 0) {
            const int row = b * 16 + r;
            *(float2*)(out + (long)row * OUT_F + f0) = make_float2(acc0, acc1);
        }
    }
}

extern "C" void kernel_launch(void* const* d_in, const int* in_sizes, int n_in,
                              void* d_out, int out_size, void* d_ws, size_t ws_size,
                              hipStream_t stream) {
    const float* x    = (const float*)d_in[0];
    const int*   row0 = (const int*)d_in[1];
    const int*   col0 = (const int*)d_in[2];
    const float* val0 = (const float*)d_in[3];
    const int*   row1 = (const int*)d_in[4];
    const int*   col1 = (const int*)d_in[5];
    const float* val1 = (const float*)d_in[6];
    const float* W0   = (const float*)d_in[7];
    const float* b0   = (const float*)d_in[8];
    const float* W1   = (const float*)d_in[9];
    const float* b1   = (const float*)d_in[10];
    float* out = (float*)d_out;

    // Workspace: sup0 (12.8 MB), sup1 (6.4 MB), bcv0/1 (9.6 MB each),
    // gfill, wt0, wt1.  Total ~39 MB.
    __half* sup0 = (__half*)d_ws;
    __half* sup1 = sup0 + (long)N_NODES * HID_F;
    int2* bcv0   = (int2*)(sup1 + (long)N_NODES * OUT_F);
    int2* bcv1   = bcv0 + (long)NBUCK * BCAP;
    int*  gfill  = (int*)(bcv1 + (long)NBUCK * BCAP);
    __half* wt0  = (__half*)(gfill + 2 * NBUCK + 2);   // [HID_F][IN_F]
    __half* wt1  = wt0 + IN_F * HID_F;                 // [OUT_F][HID_F]

    // ---- Prep (zero gfill + weight transpose) ----
    prep_kernel<<<(IN_F * HID_F + 255) / 256, 256, 0, stream>>>(W0, W1, wt0, wt1, gfill);

    // ---- Bin (both graphs) || layer-0 GEMM, one dispatch ----
    bin_gemm_kernel<<<dim3(G0_NB, 3), BIN_T, 0, stream>>>(
        row0, col0, val0, row1, col1, val1, gfill, bcv0, bcv1,
        x, wt0, sup0, N_NODES);

    // ---- Fused: LDS-sort + layer-0 aggregate + bias/relu + layer-1 GEMM ----
    agg_gemm_kernel<<<NBUCK, 256, 0, stream>>>(gfill, bcv0, sup0, b0, wt1, sup1);

    // ---- Layer-1 aggregate (LDS-sort + register acc) ----
    spmm_l1_kernel<<<NBUCK, 256, 0, stream>>>(gfill, bcv1, sup1, b1, out);
}